// Round 23
// baseline (208.742 us; speedup 1.0000x reference)
//
#include <hip/hip_runtime.h>
#include <cstdint>

// ---------------------------------------------------------------------------
// GroupedQueryAttention: B=2 N=2048 DIM=2048 HQ=16 HKV=4 HD=128, causal, RoPE.
// f32 I/O, bf16 internals. Round 23 = r22 with ONE isolated change:
//  - O-proj: stage-ahead double buffer (r21 form, never isolated): stage(t+1)
//    issued before compute(t), one barrier/round, drain lands ~600cy later.
//  - QKV (r20 dual-bn + A-reg prefetch), attn, rope/transpose: frozen.
// ---------------------------------------------------------------------------

typedef __bf16 bf16_t;
typedef __attribute__((ext_vector_type(8))) __bf16 bf16x8;
typedef __attribute__((ext_vector_type(4))) float f32x4;

#define B_    2
#define N_    2048
#define DIM_  2048
#define HQ_   16
#define HKV_  4
#define HD_   128
#define KVD_  512
#define SCALE_ 0.08838834764831845f  // 128^-0.5

// async global->LDS, 16B per lane. lds dest must be wave-uniform base.
static __device__ __forceinline__ void ld_g2l(void* lds, const void* g) {
  __builtin_amdgcn_global_load_lds((__attribute__((address_space(1))) void*)g,
                                   (__attribute__((address_space(3))) void*)lds,
                                   16, 0, 0);
}

static __device__ __forceinline__ f32x4 vmax4(f32x4 a, f32x4 b) {
  f32x4 r;
  r[0] = fmaxf(a[0], b[0]); r[1] = fmaxf(a[1], b[1]);
  r[2] = fmaxf(a[2], b[2]); r[3] = fmaxf(a[3], b[3]);
  return r;
}

// ---------------------------------------------------------------------------
// cos/sin table: [2048][64] each, f32.  inv_freq = 10000^(-i/64) (base_adj==1)
// ---------------------------------------------------------------------------
__global__ void k_sincos(float* __restrict__ cosT, float* __restrict__ sinT) {
  int idx = blockIdx.x * 256 + threadIdx.x;  // 2048*64
  int i = idx & 63;
  int n = idx >> 6;
  float inv = expf(-(float)i * (9.210340371976184f / 64.0f));  // ln(1e4)/64
  float ang = (float)n * inv;
  cosT[idx] = cosf(ang);
  sinT[idx] = sinf(ang);
}

// ---------------------------------------------------------------------------
// fused f32 -> bf16 conversion for up to four tensors (4 elems/thread)
// ---------------------------------------------------------------------------
__global__ void k_cvt4(const float* __restrict__ s0, bf16_t* __restrict__ d0, int n0,
                       const float* __restrict__ s1, bf16_t* __restrict__ d1, int n1,
                       const float* __restrict__ s2, bf16_t* __restrict__ d2, int n2,
                       const float* __restrict__ s3, bf16_t* __restrict__ d3, int n3)
{
  int i = (blockIdx.x * 256 + threadIdx.x) * 4;
  const float* s; bf16_t* d; int off;
  if (i < n0)                     { s = s0; d = d0; off = i; }
  else if (i < n0 + n1)           { s = s1; d = d1; off = i - n0; }
  else if (i < n0 + n1 + n2)      { s = s2; d = d2; off = i - n0 - n1; }
  else if (i < n0 + n1 + n2 + n3) { s = s3; d = d3; off = i - n0 - n1 - n2; }
  else return;
  f32x4 v = *(const f32x4*)(s + off);
  union { bf16_t h[4]; uint2 u; } pk;
  pk.h[0] = (bf16_t)v[0]; pk.h[1] = (bf16_t)v[1];
  pk.h[2] = (bf16_t)v[2]; pk.h[3] = (bf16_t)v[3];
  *(uint2*)(d + off) = pk.u;
}

// ---------------------------------------------------------------------------
// QKV projections (r20): dual-bn + A-reg prefetch. One staged A f32 tile
// [128][64] feeds TWO 128-col W bf16 tiles; A loads for round t+1 issued
// before round t's compute. BK=64, XOR swizzle byte^((row&7)<<4).
// z=0 Q (by<8), z=1 K, z=2 V (by<2). LDS 48KB.
// ---------------------------------------------------------------------------
__global__ __launch_bounds__(256, 2) void k_gemm_qkv(
    const float* __restrict__ q, const bf16_t* __restrict__ Wqb,
    const float* __restrict__ bq, bf16_t* __restrict__ Qp,
    const float* __restrict__ k, const bf16_t* __restrict__ Wkb,
    const float* __restrict__ bk, bf16_t* __restrict__ Kp,
    const float* __restrict__ v, const bf16_t* __restrict__ Wvb,
    const float* __restrict__ bv, bf16_t* __restrict__ Vp)
{
  __shared__ bf16_t As[128 * 64];
  __shared__ bf16_t Bs[2][128 * 64];
  const int z = blockIdx.z;
  if (z != 0 && blockIdx.y >= 2) return;
  const float* A; const bf16_t* W; const float* bias; bf16_t* C; int Nn;
  if (z == 0)      { A = q; W = Wqb; bias = bq; C = Qp; Nn = 2048; }
  else if (z == 1) { A = k; W = Wkb; bias = bk; C = Kp; Nn = 512; }
  else             { A = v; W = Wvb; bias = bv; C = Vp; Nn = 512; }

  const int tid  = threadIdx.x;
  const int lane = tid & 63;
  const int wave = tid >> 6;
  const int l15  = lane & 15;
  const int lg   = lane >> 4;
  const int bm = blockIdx.x;
  const int bn0 = blockIdx.y * 2, bn1 = bn0 + 1;
  const int wr = (wave >> 1) * 64, wc = (wave & 1) * 64;
  const int K = 2048;

  f32x4 acc0[4][4] = {};
  f32x4 acc1[4][4] = {};

  uint8_t* AsB = (uint8_t*)As;
  uint8_t* Bs0 = (uint8_t*)Bs[0];
  uint8_t* Bs1 = (uint8_t*)Bs[1];
  const uint8_t* Wb0 = (const uint8_t*)W + (size_t)(bn0 * 128) * K * 2;
  const uint8_t* Wb1 = (const uint8_t*)W + (size_t)(bn1 * 128) * K * 2;

  f32x4 arLo[4], arHi[4];   // A f32 prefetch: 32 elems/thread

  auto loadA = [&](int k0) {
#pragma unroll
    for (int i = 0; i < 4; ++i) {
      int c = i * 256 + tid;
      int row = c >> 3;
      int k8  = (c & 7) * 8;
      const float* ap = A + (size_t)(bm * 128 + row) * K + k0 + k8;
      arLo[i] = *(const f32x4*)ap;
      arHi[i] = *(const f32x4*)(ap + 4);
    }
  };
  auto writeA = [&]() {
#pragma unroll
    for (int i = 0; i < 4; ++i) {
      int c = i * 256 + tid;
      int row = c >> 3;
      int k8  = (c & 7) * 8;
      bf16x8 va;
      f32x4 lo = arLo[i], hi = arHi[i];
      va[0] = (bf16_t)lo[0]; va[1] = (bf16_t)lo[1];
      va[2] = (bf16_t)lo[2]; va[3] = (bf16_t)lo[3];
      va[4] = (bf16_t)hi[0]; va[5] = (bf16_t)hi[1];
      va[6] = (bf16_t)hi[2]; va[7] = (bf16_t)hi[3];
      int sw = (k8 * 2) ^ ((row & 7) << 4);
      *(bf16x8*)(AsB + row * 128 + sw) = va;
    }
  };

  loadA(0);   // prologue

  for (int k0 = 0; k0 < K; k0 += 64) {
#pragma unroll
    for (int r = 0; r < 4; ++r) {
      int o = r * 4096 + wave * 1024 + lane * 16;
      int row = o >> 7;
      int colB = (o & 127) ^ ((row & 7) << 4);
      size_t goff = (size_t)row * (K * 2) + (size_t)k0 * 2 + colB;
      ld_g2l(Bs0 + r * 4096 + wave * 1024, Wb0 + goff);
      ld_g2l(Bs1 + r * 4096 + wave * 1024, Wb1 + goff);
    }
    writeA();                 // cvt + ds_write only (loads already arrived)
    const bool more = (k0 + 64 < K);
    __syncthreads();          // W staged, A visible
    if (more) loadA(k0 + 64); // issue next A loads; hidden by MFMAs
    __builtin_amdgcn_s_setprio(1);
#pragma unroll
    for (int kk = 0; kk < 2; ++kk) {
      const int koff = kk * 64 + (lg << 4);
      bf16x8 fa[4], fb[4];
#pragma unroll
      for (int fi = 0; fi < 4; ++fi) {
        int row = wr + fi * 16 + l15;
        fa[fi] = *(const bf16x8*)(AsB + row * 128 + (koff ^ ((row & 7) << 4)));
      }
#pragma unroll
      for (int fj = 0; fj < 4; ++fj) {
        int row = wc + fj * 16 + l15;
        fb[fj] = *(const bf16x8*)(Bs0 + row * 128 + (koff ^ ((row & 7) << 4)));
      }
#pragma unroll
      for (int fi = 0; fi < 4; ++fi)
#pragma unroll
        for (int fj = 0; fj < 4; ++fj)
          acc0[fi][fj] = __builtin_amdgcn_mfma_f32_16x16x32_bf16(
              fa[fi], fb[fj], acc0[fi][fj], 0, 0, 0);
#pragma unroll
      for (int fj = 0; fj < 4; ++fj) {
        int row = wc + fj * 16 + l15;
        fb[fj] = *(const bf16x8*)(Bs1 + row * 128 + (koff ^ ((row & 7) << 4)));
      }
#pragma unroll
      for (int fi = 0; fi < 4; ++fi)
#pragma unroll
        for (int fj = 0; fj < 4; ++fj)
          acc1[fi][fj] = __builtin_amdgcn_mfma_f32_16x16x32_bf16(
              fa[fi], fb[fj], acc1[fi][fj], 0, 0, 0);
    }
    __builtin_amdgcn_s_setprio(0);
    __syncthreads();
  }

  const int r0 = lg * 4;
#pragma unroll
  for (int fi = 0; fi < 4; ++fi) {
#pragma unroll
    for (int rr = 0; rr < 4; ++rr) {
      int grow = bm * 128 + wr + fi * 16 + r0 + rr;
      size_t rowoff = (size_t)grow * Nn;
#pragma unroll
      for (int fj = 0; fj < 4; ++fj) {
        int gc0 = bn0 * 128 + wc + fj * 16 + l15;
        int gc1 = bn1 * 128 + wc + fj * 16 + l15;
        C[rowoff + gc0] = (bf16_t)(acc0[fi][fj][rr] + bias[gc0]);
        C[rowoff + gc1] = (bf16_t)(acc1[fi][fj][rr] + bias[gc1]);
      }
    }
  }
}

// ---------------------------------------------------------------------------
// O projection: stage-ahead double buffer (r21 form, isolated this round):
// A bf16 g2l, W bf16 g2l, C f32. 128x128, BK=64. stage(t+1) issued before
// compute(t); one barrier per round. LDS 64KB, lb(256,2).
// ---------------------------------------------------------------------------
__global__ __launch_bounds__(256, 2) void k_gemm_o(
    const bf16_t* __restrict__ Ain, const bf16_t* __restrict__ Wob,
    const float* __restrict__ bo, float* __restrict__ out)
{
  __shared__ bf16_t As[2][128 * 64];
  __shared__ bf16_t Bs[2][128 * 64];
  const int tid  = threadIdx.x;
  const int lane = tid & 63;
  const int wave = tid >> 6;
  const int l15  = lane & 15;
  const int lg   = lane >> 4;
  const int bm = blockIdx.x, bn = blockIdx.y;
  const int wr = (wave >> 1) * 64, wc = (wave & 1) * 64;
  const int K = 2048, N = 2048;

  f32x4 acc[4][4] = {};
  const uint8_t* Wbase = (const uint8_t*)Wob + (size_t)(bn * 128) * K * 2;
  const uint8_t* Abase = (const uint8_t*)Ain + (size_t)(bm * 128) * K * 2;

  auto stage = [&](int buf, int k0) {
    uint8_t* Ad = (uint8_t*)As[buf];
    uint8_t* Bd = (uint8_t*)Bs[buf];
#pragma unroll
    for (int r = 0; r < 4; ++r) {
      int o = r * 4096 + wave * 1024 + lane * 16;
      int row = o >> 7;
      int colB = (o & 127) ^ ((row & 7) << 4);
      size_t goff = (size_t)row * (K * 2) + (size_t)k0 * 2 + colB;
      ld_g2l(Bd + r * 4096 + wave * 1024, Wbase + goff);
      ld_g2l(Ad + r * 4096 + wave * 1024, Abase + goff);
    }
  };

  stage(0, 0);
  __syncthreads();
  int cur = 0;

  for (int k0 = 0; k0 < K; k0 += 64) {
    if (k0 + 64 < K) stage(cur ^ 1, k0 + 64);   // async; drains post-compute
    const uint8_t* Ar = (const uint8_t*)As[cur];
    const uint8_t* Br = (const uint8_t*)Bs[cur];
    __builtin_amdgcn_s_setprio(1);
#pragma unroll
    for (int kk = 0; kk < 2; ++kk) {
      const int koff = kk * 64 + (lg << 4);
      bf16x8 fa[4], fb[4];
#pragma unroll
      for (int fi = 0; fi < 4; ++fi) {
        int row = wr + fi * 16 + l15;
        fa[fi] = *(const bf16x8*)(Ar + row * 128 + (koff ^ ((row & 7) << 4)));
      }
#pragma unroll
      for (int fj = 0; fj < 4; ++fj) {
        int row = wc + fj * 16 + l15;
        fb[fj] = *(const bf16x8*)(Br + row * 128 + (koff ^ ((row & 7) << 4)));
      }
#pragma unroll
      for (int fi = 0; fi < 4; ++fi)
#pragma unroll
        for (int fj = 0; fj < 4; ++fj)
          acc[fi][fj] = __builtin_amdgcn_mfma_f32_16x16x32_bf16(
              fa[fi], fb[fj], acc[fi][fj], 0, 0, 0);
    }
    __builtin_amdgcn_s_setprio(0);
    __syncthreads();
    cur ^= 1;
  }

  const int r0 = lg * 4;
#pragma unroll
  for (int fi = 0; fi < 4; ++fi) {
#pragma unroll
    for (int rr = 0; rr < 4; ++rr) {
      int grow = bm * 128 + wr + fi * 16 + r0 + rr;
      size_t rowoff = (size_t)grow * N;
#pragma unroll
      for (int fj = 0; fj < 4; ++fj) {
        int gcol = bn * 128 + wc + fj * 16 + l15;
        out[rowoff + gcol] = acc[fi][fj][rr] + bo[gcol];
      }
    }
  }
}

// ---------------------------------------------------------------------------
// Merged: blocks [0,512) = RoPE on Kp (lgnh=2); blocks [512,1024) = V transpose.
// ---------------------------------------------------------------------------
__global__ void k_ropek_transv(bf16_t* __restrict__ Kp,
                               const float* __restrict__ cosT,
                               const float* __restrict__ sinT,
                               const bf16_t* __restrict__ Vp,
                               bf16_t* __restrict__ Vt)
{
  __shared__ bf16_t tile[64][72];
  const int tid = threadIdx.x;
  if (blockIdx.x < 512) {
    int idx = blockIdx.x * 256 + tid;
    int j = idx & 7;
    int h = (idx >> 3) & 3;
    int row = idx >> 5;
    int n = row & (N_ - 1);
    int d0 = j * 8;
    const float* cp = cosT + (n << 6) + d0;
    const float* sp = sinT + (n << 6) + d0;
    f32x4 c0 = *(const f32x4*)cp,  c1 = *(const f32x4*)(cp + 4);
    f32x4 s0 = *(const f32x4*)sp,  s1 = *(const f32x4*)(sp + 4);
    bf16_t* xb = Kp + (size_t)row * 512 + (h << 7) + d0;
    bf16x8 x1 = *(const bf16x8*)xb;
    bf16x8 x2 = *(const bf16x8*)(xb + 64);
    bf16x8 o1, o2;
#pragma unroll
    for (int e = 0; e < 8; ++e) {
      float c = e < 4 ? c0[e] : c1[e - 4];
      float s = e < 4 ? s0[e] : s1[e - 4];
      float a = (float)x1[e], bvl = (float)x2[e];
      o1[e] = (bf16_t)(a * c - bvl * s);
      o2[e] = (bf16_t)(bvl * c + a * s);
    }
    *(bf16x8*)xb = o1;
    *(bf16x8*)(xb + 64) = o2;
    return;
  }
  const int bid = blockIdx.x - 512;
  const int r0 = (bid & 63) * 64;
  const int d0 = (bid >> 6) * 64;
  for (int r = 0; r < 2; ++r) {
    int n = r * 32 + (tid >> 3);
    int dc = (tid & 7) * 8;
    *(uint4*)&tile[n][dc] = *(const uint4*)(Vp + (size_t)(r0 + n) * KVD_ + d0 + dc);
  }
  __syncthreads();
  const int b = r0 >> 11;
  const int nseq = r0 & (N_ - 1);
  for (int r = 0; r < 2; ++r) {
    int dd = r * 32 + (tid >> 3);
    int nc = (tid & 7) * 8;
    int dglob = d0 + dd;
    int hkv = dglob >> 7, dloc = dglob & 127;
    union { bf16_t h[8]; uint4 v; } pk;
    for (int j = 0; j < 8; ++j) pk.h[j] = tile[nc + j][dd];
    size_t drow = (size_t)(b * HKV_ + hkv) * 128 + dloc;
    *(uint4*)(Vt + drow * N_ + nseq + nc) = pk.v;
  }
}

// ---------------------------------------------------------------------------
// Flash attention, causal GQA (r18): fused RoPE-Q prologue, complementary
// pairing, dbuf K/V staging, swapped-operand lane-local softmax + defer-max,
// setprio, output in-place into Qp.
// ---------------------------------------------------------------------------
__global__ __launch_bounds__(256, 2) void k_attn(
    const bf16_t* __restrict__ Qp, const bf16_t* __restrict__ Kp,
    const bf16_t* __restrict__ Vt, bf16_t* __restrict__ AO,
    const float* __restrict__ cosT, const float* __restrict__ sinT)
{
  __shared__ bf16_t Ks[2][64 * 128];
  __shared__ bf16_t Vs[2][128 * 64];
  __shared__ bf16_t Ps[4][16 * 72];
  const int tid = threadIdx.x, lane = tid & 63, wave = tid >> 6;
  const int l15 = lane & 15, lg = lane >> 4;
  const int bx = (blockIdx.y < 16) ? (15 - (int)blockIdx.x) : (int)blockIdx.x;
  const int qtile = bx * 4 + wave;
  const int bh = blockIdx.y;
  const int b = bh >> 4, hq = bh & 15, hkv = hq >> 2;

  bf16x8 qf[2][4];
#pragma unroll
  for (int rf = 0; rf < 2; ++rf) {
    int n = qtile * 32 + rf * 16 + l15;
    size_t qrow = (size_t)b * N_ + n;
    const uint8_t* qb = (const uint8_t*)Qp + (qrow * DIM_ + (size_t)hq * HD_) * 2 + lg * 16;
#pragma unroll
    for (int ks = 0; ks < 4; ++ks)
      qf[rf][ks] = *(const bf16x8*)(qb + ks * 64);
    const float* cb = cosT + n * 64 + lg * 8;
    const float* sb = sinT + n * 64 + lg * 8;
    f32x4 c0a = *(const f32x4*)cb,        c0b = *(const f32x4*)(cb + 4);
    f32x4 c1a = *(const f32x4*)(cb + 32), c1b = *(const f32x4*)(cb + 36);
    f32x4 s0a = *(const f32x4*)sb,        s0b = *(const f32x4*)(sb + 4);
    f32x4 s1a = *(const f32x4*)(sb + 32), s1b = *(const f32x4*)(sb + 36);
#pragma unroll
    for (int e = 0; e < 8; ++e) {
      float c0 = e < 4 ? c0a[e] : c0b[e - 4], s0 = e < 4 ? s0a[e] : s0b[e - 4];
      float c1 = e < 4 ? c1a[e] : c1b[e - 4], s1 = e < 4 ? s1a[e] : s1b[e - 4];
      float a0 = (float)qf[rf][0][e], b0 = (float)qf[rf][2][e];
      float a1 = (float)qf[rf][1][e], b1 = (float)qf[rf][3][e];
      qf[rf][0][e] = (bf16_t)((a0 * c0 - b0 * s0) * SCALE_);
      qf[rf][2][e] = (bf16_t)((b0 * c0 + a0 * s0) * SCALE_);
      qf[rf][1][e] = (bf16_t)((a1 * c1 - b1 * s1) * SCALE_);
      qf[rf][3][e] = (bf16_t)((b1 * c1 + a1 * s1) * SCALE_);
    }
  }

  float m[2] = {-1e30f, -1e30f};
  float ln[2] = {0.f, 0.f};
  f32x4 o[2][8] = {};

  const uint8_t* KpB = (const uint8_t*)Kp + ((size_t)b * N_ * KVD_ + (size_t)hkv * HD_) * 2;
  const uint8_t* VtB = (const uint8_t*)Vt + (size_t)(b * HKV_ + hkv) * HD_ * (size_t)N_ * 2;
  uint8_t* PwB = (uint8_t*)Ps[wave];

  const int Tw   = qtile / 2 + 1;
  const int Tmax = 2 * bx + 2;

  auto stage = [&](int buf, int t) {
    uint8_t* KsB = (uint8_t*)Ks[buf];
    uint8_t* VsB = (uint8_t*)Vs[buf];
#pragma unroll
    for (int r = 0; r < 4; ++r) {
      int o16 = r * 4096 + wave * 1024 + lane * 16;
      int row = o16 >> 8;
      int colB = (o16 & 255) ^ ((row & 7) << 4);
      ld_g2l(KsB + r * 4096 + wave * 1024,
             KpB + (size_t)(t * 64 + row) * (KVD_ * 2) + colB);
    }
#pragma unroll
    for (int r = 0; r < 4; ++r) {
      int o16 = r * 4096 + wave * 1024 + lane * 16;
      int dd = o16 >> 7;
      int colB = (o16 & 127) ^ ((dd & 7) << 4);
      ld_g2l(VsB + r * 4096 + wave * 1024,
             VtB + (size_t)dd * (N_ * 2) + t * 128 + colB);
    }
  };

  stage(0, 0);
  __syncthreads();
  int cur = 0;

  for (int t = 0; t < Tmax; ++t) {
    if (t + 1 < Tmax) stage(cur ^ 1, t + 1);

    if (t < Tw) {
      const uint8_t* KsB = (const uint8_t*)Ks[cur];
      const uint8_t* VsB = (const uint8_t*)Vs[cur];

      f32x4 s4[2][4] = {};
      __builtin_amdgcn_s_setprio(1);
#pragma unroll
      for (int ks = 0; ks < 4; ++ks) {
        int koff = ks * 64 + lg * 16;
#pragma unroll
        for (int kb = 0; kb < 4; ++kb) {
          int row = kb * 16 + l15;
          bf16x8 kf = *(const bf16x8*)(KsB + row * 256 + (koff ^ ((row & 7) << 4)));
          s4[0][kb] = __builtin_amdgcn_mfma_f32_16x16x32_bf16(kf, qf[0][ks], s4[0][kb], 0, 0, 0);
          s4[1][kb] = __builtin_amdgcn_mfma_f32_16x16x32_bf16(kf, qf[1][ks], s4[1][kb], 0, 0, 0);
        }
      }
      __builtin_amdgcn_s_setprio(0);

      if (t == Tw - 1) {
#pragma unroll
        for (int rf = 0; rf < 2; ++rf) {
          int q = qtile * 32 + rf * 16 + l15;
#pragma unroll
          for (int kb = 0; kb < 4; ++kb) {
            int key = t * 64 + kb * 16 + lg * 4;
#pragma unroll
            for (int rr = 0; rr < 4; ++rr)
              if (key + rr > q) s4[rf][kb][rr] = -1e30f;
          }
        }
      }

      bf16x8 pf[2][2];
#pragma unroll
      for (int rf = 0; rf < 2; ++rf) {
        f32x4 mx = vmax4(vmax4(s4[rf][0], s4[rf][1]), vmax4(s4[rf][2], s4[rf][3]));
        float rm = fmaxf(fmaxf(mx[0], mx[1]), fmaxf(mx[2], mx[3]));
        rm = fmaxf(rm, __shfl_xor(rm, 16));
        rm = fmaxf(rm, __shfl_xor(rm, 32));

        const bool defer = __all(rm <= m[rf] + 8.0f);
        float mn = defer ? m[rf] : fmaxf(m[rf], rm);
        float sc = defer ? 1.0f : __expf(m[rf] - mn);

        f32x4 p[4];
        f32x4 psum = {0.f, 0.f, 0.f, 0.f};
#pragma unroll
        for (int kb = 0; kb < 4; ++kb) {
#pragma unroll
          for (int rr = 0; rr < 4; ++rr)
            p[kb][rr] = __expf(s4[rf][kb][rr] - mn);
          psum += p[kb];
        }
        float rs = (psum[0] + psum[1]) + (psum[2] + psum[3]);
        rs += __shfl_xor(rs, 16);
        rs += __shfl_xor(rs, 32);
        ln[rf] = ln[rf] * sc + rs;
        m[rf] = mn;

        if (!defer) {
#pragma unroll
          for (int db = 0; db < 8; ++db) o[rf][db] *= sc;
        }

#pragma unroll
        for (int kb = 0; kb < 4; ++kb) {
          union { bf16_t h[4]; uint2 u; } pk;
          pk.h[0] = (bf16_t)p[kb][0]; pk.h[1] = (bf16_t)p[kb][1];
          pk.h[2] = (bf16_t)p[kb][2]; pk.h[3] = (bf16_t)p[kb][3];
          *(uint2*)(PwB + l15 * 144 + kb * 32 + lg * 8) = pk.u;
        }
        pf[rf][0] = *(const bf16x8*)(PwB + l15 * 144 + lg * 16);
        pf[rf][1] = *(const bf16x8*)(PwB + l15 * 144 + 64 + lg * 16);
      }

      __builtin_amdgcn_s_setprio(1);
#pragma unroll
      for (int ks2 = 0; ks2 < 2; ++ks2) {
        int koff = ks2 * 64 + lg * 16;
#pragma unroll
        for (int db = 0; db < 8; ++db) {
          int dd = db * 16 + l15;
          bf16x8 vf = *(const bf16x8*)(VsB + dd * 128 + (koff ^ ((dd & 7) << 4)));
          o[0][db] = __builtin_amdgcn_mfma_f32_16x16x32_bf16(vf, pf[0][ks2], o[0][db], 0, 0, 0);
          o[1][db] = __builtin_amdgcn_mfma_f32_16x16x32_bf16(vf, pf[1][ks2], o[1][db], 0, 0, 0);
        }
      }
      __builtin_amdgcn_s_setprio(0);
    }

    __syncthreads();
    cur ^= 1;
  }

#pragma unroll
  for (int rf = 0; rf < 2; ++rf) {
    float iv = 1.f / ln[rf];
    size_t qrow = (size_t)b * N_ + qtile * 32 + rf * 16 + l15;
    uint8_t* ob = (uint8_t*)(AO + qrow * DIM_ + (size_t)hq * HD_);
#pragma unroll
    for (int db = 0; db < 8; ++db) {
      union { bf16_t h[4]; uint2 u; } pk;
      pk.h[0] = (bf16_t)(o[rf][db][0] * iv);
      pk.h[1] = (bf16_t)(o[rf][db][1] * iv);
      pk.h[2] = (bf16_t)(o[rf][db][2] * iv);
      pk.h[3] = (bf16_t)(o[rf][db][3] * iv);
      *(uint2*)(ob + (db * 16 + lg * 4) * 2) = pk.u;
    }
  }
}

// ---------------------------------------------------------------------------
extern "C" void kernel_launch(void* const* d_in, const int* in_sizes, int n_in,
                              void* d_out, int out_size, void* d_ws, size_t ws_size,
                              hipStream_t stream)
{
  if (ws_size < (46u << 20)) return;  // proven sufficient in rounds 3-22

  const float* query = (const float*)d_in[0];
  const float* key   = (const float*)d_in[1];
  const float* value = (const float*)d_in[2];
  const float* Wq = (const float*)d_in[3];
  const float* bq = (const float*)d_in[4];
  const float* Wk = (const float*)d_in[5];
  const float* bk = (const float*)d_in[6];
  const float* Wv = (const float*)d_in[7];
  const float* bv = (const float*)d_in[8];
  const float* Wo = (const float*)d_in[9];
  const float* bo = (const float*)d_in[10];
  float* out = (float*)d_out;

  uint8_t* ws = (uint8_t*)d_ws;
  float*  cosT = (float*)(ws);                       // 0.5 MB
  float*  sinT = (float*)(ws + (512u << 10));        // 0.5 MB
  bf16_t* Qp   = (bf16_t*)(ws + (1u  << 20));        // 16 MB [4096][2048] (+ attn out)
  bf16_t* Kp   = (bf16_t*)(ws + (17u << 20));        // 4 MB  [4096][512]
  bf16_t* Vp   = (bf16_t*)(ws + (21u << 20));        // 4 MB  [4096][512]
  bf16_t* Vt   = (bf16_t*)(ws + (25u << 20));        // 4 MB  [8][128][2048]
  bf16_t* Wqb  = (bf16_t*)(ws + (29u << 20));        // 8 MB  [2048][2048]
  bf16_t* Wkb  = (bf16_t*)(ws + (37u << 20));        // 2 MB  [512][2048]
  bf16_t* Wvb  = (bf16_t*)(ws + (39u << 20));        // 2 MB  [512][2048]
  bf16_t* WobL = (bf16_t*)(ws + (17u << 20));        // late path: over Kp+Vp
  bf16_t* WobE = (bf16_t*)(ws + (41u << 20));        // early path: 8 MB at 41MB

  const bool bigws = ws_size >= (50ull << 20);       // early-Wo needs 49 MB

  k_sincos<<<512, 256, 0, stream>>>(cosT, sinT);

  if (bigws) {
    k_cvt4<<<10240, 256, 0, stream>>>(Wq, Wqb, 4194304,
                                      Wk, Wkb, 1048576,
                                      Wv, Wvb, 1048576,
                                      Wo, WobE, 4194304);
  } else {
    k_cvt4<<<6144, 256, 0, stream>>>(Wq, Wqb, 4194304,
                                     Wk, Wkb, 1048576,
                                     Wv, Wvb, 1048576,
                                     nullptr, nullptr, 0);
  }

  // Q+K+V projections: dual-bn + A-reg prefetch (r20 exact)
  k_gemm_qkv<<<dim3(32, 8, 3), 256, 0, stream>>>(
      query, Wqb, bq, Qp, key, Wkb, bk, Kp, value, Wvb, bv, Vp);

  // merged RoPE-K + V-transpose (one launch)
  k_ropek_transv<<<1024, 256, 0, stream>>>(Kp, cosT, sinT, Vp, Vt);

  // flash attention: fused RoPE-Q + complementary pairing + dbuf staging
  k_attn<<<dim3(16, 32), 256, 0, stream>>>(Qp, Kp, Vt, Qp, cosT, sinT);

  if (!bigws) {
    k_cvt4<<<4096, 256, 0, stream>>>(Wo, WobL, 4194304,
                                     nullptr, nullptr, 0,
                                     nullptr, nullptr, 0,
                                     nullptr, nullptr, 0);
  }

  // Output projection: stage-ahead dbuf (isolated r21 change)
  k_gemm_o<<<dim3(32, 16), 256, 0, stream>>>(
      Qp, bigws ? WobE : WobL, bo, out);
}

// Round 24
// 204.935 us; speedup vs baseline: 1.0186x; 1.0186x over previous
//
#include <hip/hip_runtime.h>
#include <cstdint>

// ---------------------------------------------------------------------------
// GroupedQueryAttention: B=2 N=2048 DIM=2048 HQ=16 HKV=4 HD=128, causal, RoPE.
// f32 I/O, bf16 internals. Round 24 = best configuration (r20/r22, 204.0us):
//  - QKV: dual-bn + A-reg prefetch (48KB LDS, lb(256,2))
//  - O-proj: single-buffer full-g2l (lb(256,4))  [r23 dbuf reverted: -3us]
//  - attn: fused RoPE-Q, complementary pairing, dbuf K/V staging, defer-max
//  - cvt4 early weights, merged ropeK+transV, in-place attn output
// ---------------------------------------------------------------------------

typedef __bf16 bf16_t;
typedef __attribute__((ext_vector_type(8))) __bf16 bf16x8;
typedef __attribute__((ext_vector_type(4))) float f32x4;

#define B_    2
#define N_    2048
#define DIM_  2048
#define HQ_   16
#define HKV_  4
#define HD_   128
#define KVD_  512
#define SCALE_ 0.08838834764831845f  // 128^-0.5

// async global->LDS, 16B per lane. lds dest must be wave-uniform base.
static __device__ __forceinline__ void ld_g2l(void* lds, const void* g) {
  __builtin_amdgcn_global_load_lds((__attribute__((address_space(1))) void*)g,
                                   (__attribute__((address_space(3))) void*)lds,
                                   16, 0, 0);
}

static __device__ __forceinline__ f32x4 vmax4(f32x4 a, f32x4 b) {
  f32x4 r;
  r[0] = fmaxf(a[0], b[0]); r[1] = fmaxf(a[1], b[1]);
  r[2] = fmaxf(a[2], b[2]); r[3] = fmaxf(a[3], b[3]);
  return r;
}

// ---------------------------------------------------------------------------
// cos/sin table: [2048][64] each, f32.  inv_freq = 10000^(-i/64) (base_adj==1)
// ---------------------------------------------------------------------------
__global__ void k_sincos(float* __restrict__ cosT, float* __restrict__ sinT) {
  int idx = blockIdx.x * 256 + threadIdx.x;  // 2048*64
  int i = idx & 63;
  int n = idx >> 6;
  float inv = expf(-(float)i * (9.210340371976184f / 64.0f));  // ln(1e4)/64
  float ang = (float)n * inv;
  cosT[idx] = cosf(ang);
  sinT[idx] = sinf(ang);
}

// ---------------------------------------------------------------------------
// fused f32 -> bf16 conversion for up to four tensors (4 elems/thread)
// ---------------------------------------------------------------------------
__global__ void k_cvt4(const float* __restrict__ s0, bf16_t* __restrict__ d0, int n0,
                       const float* __restrict__ s1, bf16_t* __restrict__ d1, int n1,
                       const float* __restrict__ s2, bf16_t* __restrict__ d2, int n2,
                       const float* __restrict__ s3, bf16_t* __restrict__ d3, int n3)
{
  int i = (blockIdx.x * 256 + threadIdx.x) * 4;
  const float* s; bf16_t* d; int off;
  if (i < n0)                     { s = s0; d = d0; off = i; }
  else if (i < n0 + n1)           { s = s1; d = d1; off = i - n0; }
  else if (i < n0 + n1 + n2)      { s = s2; d = d2; off = i - n0 - n1; }
  else if (i < n0 + n1 + n2 + n3) { s = s3; d = d3; off = i - n0 - n1 - n2; }
  else return;
  f32x4 v = *(const f32x4*)(s + off);
  union { bf16_t h[4]; uint2 u; } pk;
  pk.h[0] = (bf16_t)v[0]; pk.h[1] = (bf16_t)v[1];
  pk.h[2] = (bf16_t)v[2]; pk.h[3] = (bf16_t)v[3];
  *(uint2*)(d + off) = pk.u;
}

// ---------------------------------------------------------------------------
// QKV projections: dual-bn + A-reg prefetch. One staged A f32 tile [128][64]
// feeds TWO 128-col W bf16 tiles; A loads for round t+1 issued after the
// barrier, hidden under the 64-MFMA compute. BK=64, XOR swizzle
// byte^((row&7)<<4). z=0 Q (by<8), z=1 K, z=2 V (by<2). LDS 48KB.
// ---------------------------------------------------------------------------
__global__ __launch_bounds__(256, 2) void k_gemm_qkv(
    const float* __restrict__ q, const bf16_t* __restrict__ Wqb,
    const float* __restrict__ bq, bf16_t* __restrict__ Qp,
    const float* __restrict__ k, const bf16_t* __restrict__ Wkb,
    const float* __restrict__ bk, bf16_t* __restrict__ Kp,
    const float* __restrict__ v, const bf16_t* __restrict__ Wvb,
    const float* __restrict__ bv, bf16_t* __restrict__ Vp)
{
  __shared__ bf16_t As[128 * 64];
  __shared__ bf16_t Bs[2][128 * 64];
  const int z = blockIdx.z;
  if (z != 0 && blockIdx.y >= 2) return;
  const float* A; const bf16_t* W; const float* bias; bf16_t* C; int Nn;
  if (z == 0)      { A = q; W = Wqb; bias = bq; C = Qp; Nn = 2048; }
  else if (z == 1) { A = k; W = Wkb; bias = bk; C = Kp; Nn = 512; }
  else             { A = v; W = Wvb; bias = bv; C = Vp; Nn = 512; }

  const int tid  = threadIdx.x;
  const int lane = tid & 63;
  const int wave = tid >> 6;
  const int l15  = lane & 15;
  const int lg   = lane >> 4;
  const int bm = blockIdx.x;
  const int bn0 = blockIdx.y * 2, bn1 = bn0 + 1;
  const int wr = (wave >> 1) * 64, wc = (wave & 1) * 64;
  const int K = 2048;

  f32x4 acc0[4][4] = {};
  f32x4 acc1[4][4] = {};

  uint8_t* AsB = (uint8_t*)As;
  uint8_t* Bs0 = (uint8_t*)Bs[0];
  uint8_t* Bs1 = (uint8_t*)Bs[1];
  const uint8_t* Wb0 = (const uint8_t*)W + (size_t)(bn0 * 128) * K * 2;
  const uint8_t* Wb1 = (const uint8_t*)W + (size_t)(bn1 * 128) * K * 2;

  f32x4 arLo[4], arHi[4];   // A f32 prefetch: 32 elems/thread

  auto loadA = [&](int k0) {
#pragma unroll
    for (int i = 0; i < 4; ++i) {
      int c = i * 256 + tid;
      int row = c >> 3;
      int k8  = (c & 7) * 8;
      const float* ap = A + (size_t)(bm * 128 + row) * K + k0 + k8;
      arLo[i] = *(const f32x4*)ap;
      arHi[i] = *(const f32x4*)(ap + 4);
    }
  };
  auto writeA = [&]() {
#pragma unroll
    for (int i = 0; i < 4; ++i) {
      int c = i * 256 + tid;
      int row = c >> 3;
      int k8  = (c & 7) * 8;
      bf16x8 va;
      f32x4 lo = arLo[i], hi = arHi[i];
      va[0] = (bf16_t)lo[0]; va[1] = (bf16_t)lo[1];
      va[2] = (bf16_t)lo[2]; va[3] = (bf16_t)lo[3];
      va[4] = (bf16_t)hi[0]; va[5] = (bf16_t)hi[1];
      va[6] = (bf16_t)hi[2]; va[7] = (bf16_t)hi[3];
      int sw = (k8 * 2) ^ ((row & 7) << 4);
      *(bf16x8*)(AsB + row * 128 + sw) = va;
    }
  };

  loadA(0);   // prologue

  for (int k0 = 0; k0 < K; k0 += 64) {
#pragma unroll
    for (int r = 0; r < 4; ++r) {
      int o = r * 4096 + wave * 1024 + lane * 16;
      int row = o >> 7;
      int colB = (o & 127) ^ ((row & 7) << 4);
      size_t goff = (size_t)row * (K * 2) + (size_t)k0 * 2 + colB;
      ld_g2l(Bs0 + r * 4096 + wave * 1024, Wb0 + goff);
      ld_g2l(Bs1 + r * 4096 + wave * 1024, Wb1 + goff);
    }
    writeA();                 // cvt + ds_write only (loads already arrived)
    const bool more = (k0 + 64 < K);
    __syncthreads();          // W staged, A visible
    if (more) loadA(k0 + 64); // issue next A loads; hidden by MFMAs
    __builtin_amdgcn_s_setprio(1);
#pragma unroll
    for (int kk = 0; kk < 2; ++kk) {
      const int koff = kk * 64 + (lg << 4);
      bf16x8 fa[4], fb[4];
#pragma unroll
      for (int fi = 0; fi < 4; ++fi) {
        int row = wr + fi * 16 + l15;
        fa[fi] = *(const bf16x8*)(AsB + row * 128 + (koff ^ ((row & 7) << 4)));
      }
#pragma unroll
      for (int fj = 0; fj < 4; ++fj) {
        int row = wc + fj * 16 + l15;
        fb[fj] = *(const bf16x8*)(Bs0 + row * 128 + (koff ^ ((row & 7) << 4)));
      }
#pragma unroll
      for (int fi = 0; fi < 4; ++fi)
#pragma unroll
        for (int fj = 0; fj < 4; ++fj)
          acc0[fi][fj] = __builtin_amdgcn_mfma_f32_16x16x32_bf16(
              fa[fi], fb[fj], acc0[fi][fj], 0, 0, 0);
#pragma unroll
      for (int fj = 0; fj < 4; ++fj) {
        int row = wc + fj * 16 + l15;
        fb[fj] = *(const bf16x8*)(Bs1 + row * 128 + (koff ^ ((row & 7) << 4)));
      }
#pragma unroll
      for (int fi = 0; fi < 4; ++fi)
#pragma unroll
        for (int fj = 0; fj < 4; ++fj)
          acc1[fi][fj] = __builtin_amdgcn_mfma_f32_16x16x32_bf16(
              fa[fi], fb[fj], acc1[fi][fj], 0, 0, 0);
    }
    __builtin_amdgcn_s_setprio(0);
    __syncthreads();
  }

  const int r0 = lg * 4;
#pragma unroll
  for (int fi = 0; fi < 4; ++fi) {
#pragma unroll
    for (int rr = 0; rr < 4; ++rr) {
      int grow = bm * 128 + wr + fi * 16 + r0 + rr;
      size_t rowoff = (size_t)grow * Nn;
#pragma unroll
      for (int fj = 0; fj < 4; ++fj) {
        int gc0 = bn0 * 128 + wc + fj * 16 + l15;
        int gc1 = bn1 * 128 + wc + fj * 16 + l15;
        C[rowoff + gc0] = (bf16_t)(acc0[fi][fj][rr] + bias[gc0]);
        C[rowoff + gc1] = (bf16_t)(acc1[fi][fj][rr] + bias[gc1]);
      }
    }
  }
}

// ---------------------------------------------------------------------------
// O projection: A bf16 g2l, W bf16 g2l, C f32. 128x128, BK=64, single-buffer
// (best-measured form: lb(256,4), 32KB LDS).
// ---------------------------------------------------------------------------
__global__ __launch_bounds__(256, 4) void k_gemm_o(
    const bf16_t* __restrict__ Ain, const bf16_t* __restrict__ Wob,
    const float* __restrict__ bo, float* __restrict__ out)
{
  __shared__ bf16_t As[128 * 64];
  __shared__ bf16_t Bs[128 * 64];
  const int tid  = threadIdx.x;
  const int lane = tid & 63;
  const int wave = tid >> 6;
  const int l15  = lane & 15;
  const int lg   = lane >> 4;
  const int bm = blockIdx.x, bn = blockIdx.y;
  const int wr = (wave >> 1) * 64, wc = (wave & 1) * 64;
  const int K = 2048, N = 2048;

  f32x4 acc[4][4] = {};
  uint8_t* AsB = (uint8_t*)As;
  uint8_t* BsB = (uint8_t*)Bs;
  const uint8_t* Wbase = (const uint8_t*)Wob + (size_t)(bn * 128) * K * 2;
  const uint8_t* Abase = (const uint8_t*)Ain + (size_t)(bm * 128) * K * 2;

  for (int k0 = 0; k0 < K; k0 += 64) {
    for (int r = 0; r < 4; ++r) {
      int o = r * 4096 + wave * 1024 + lane * 16;
      int row = o >> 7;
      int colB = (o & 127) ^ ((row & 7) << 4);
      size_t goff = (size_t)row * (K * 2) + (size_t)k0 * 2 + colB;
      ld_g2l(BsB + r * 4096 + wave * 1024, Wbase + goff);
      ld_g2l(AsB + r * 4096 + wave * 1024, Abase + goff);
    }
    __syncthreads();
    for (int kk = 0; kk < 2; ++kk) {
      const int koff = kk * 64 + (lg << 4);
      bf16x8 fa[4], fb[4];
      for (int fi = 0; fi < 4; ++fi) {
        int row = wr + fi * 16 + l15;
        fa[fi] = *(const bf16x8*)(AsB + row * 128 + (koff ^ ((row & 7) << 4)));
      }
      for (int fj = 0; fj < 4; ++fj) {
        int row = wc + fj * 16 + l15;
        fb[fj] = *(const bf16x8*)(BsB + row * 128 + (koff ^ ((row & 7) << 4)));
      }
      for (int fi = 0; fi < 4; ++fi)
        for (int fj = 0; fj < 4; ++fj)
          acc[fi][fj] = __builtin_amdgcn_mfma_f32_16x16x32_bf16(
              fa[fi], fb[fj], acc[fi][fj], 0, 0, 0);
    }
    __syncthreads();
  }

  const int r0 = lg * 4;
  for (int fi = 0; fi < 4; ++fi) {
    for (int rr = 0; rr < 4; ++rr) {
      int grow = bm * 128 + wr + fi * 16 + r0 + rr;
      size_t rowoff = (size_t)grow * N;
      for (int fj = 0; fj < 4; ++fj) {
        int gcol = bn * 128 + wc + fj * 16 + l15;
        out[rowoff + gcol] = acc[fi][fj][rr] + bo[gcol];
      }
    }
  }
}

// ---------------------------------------------------------------------------
// Merged: blocks [0,512) = RoPE on Kp (lgnh=2); blocks [512,1024) = V transpose.
// ---------------------------------------------------------------------------
__global__ void k_ropek_transv(bf16_t* __restrict__ Kp,
                               const float* __restrict__ cosT,
                               const float* __restrict__ sinT,
                               const bf16_t* __restrict__ Vp,
                               bf16_t* __restrict__ Vt)
{
  __shared__ bf16_t tile[64][72];
  const int tid = threadIdx.x;
  if (blockIdx.x < 512) {
    int idx = blockIdx.x * 256 + tid;
    int j = idx & 7;
    int h = (idx >> 3) & 3;
    int row = idx >> 5;
    int n = row & (N_ - 1);
    int d0 = j * 8;
    const float* cp = cosT + (n << 6) + d0;
    const float* sp = sinT + (n << 6) + d0;
    f32x4 c0 = *(const f32x4*)cp,  c1 = *(const f32x4*)(cp + 4);
    f32x4 s0 = *(const f32x4*)sp,  s1 = *(const f32x4*)(sp + 4);
    bf16_t* xb = Kp + (size_t)row * 512 + (h << 7) + d0;
    bf16x8 x1 = *(const bf16x8*)xb;
    bf16x8 x2 = *(const bf16x8*)(xb + 64);
    bf16x8 o1, o2;
#pragma unroll
    for (int e = 0; e < 8; ++e) {
      float c = e < 4 ? c0[e] : c1[e - 4];
      float s = e < 4 ? s0[e] : s1[e - 4];
      float a = (float)x1[e], bvl = (float)x2[e];
      o1[e] = (bf16_t)(a * c - bvl * s);
      o2[e] = (bf16_t)(bvl * c + a * s);
    }
    *(bf16x8*)xb = o1;
    *(bf16x8*)(xb + 64) = o2;
    return;
  }
  const int bid = blockIdx.x - 512;
  const int r0 = (bid & 63) * 64;
  const int d0 = (bid >> 6) * 64;
  for (int r = 0; r < 2; ++r) {
    int n = r * 32 + (tid >> 3);
    int dc = (tid & 7) * 8;
    *(uint4*)&tile[n][dc] = *(const uint4*)(Vp + (size_t)(r0 + n) * KVD_ + d0 + dc);
  }
  __syncthreads();
  const int b = r0 >> 11;
  const int nseq = r0 & (N_ - 1);
  for (int r = 0; r < 2; ++r) {
    int dd = r * 32 + (tid >> 3);
    int nc = (tid & 7) * 8;
    int dglob = d0 + dd;
    int hkv = dglob >> 7, dloc = dglob & 127;
    union { bf16_t h[8]; uint4 v; } pk;
    for (int j = 0; j < 8; ++j) pk.h[j] = tile[nc + j][dd];
    size_t drow = (size_t)(b * HKV_ + hkv) * 128 + dloc;
    *(uint4*)(Vt + drow * N_ + nseq + nc) = pk.v;
  }
}

// ---------------------------------------------------------------------------
// Flash attention, causal GQA: fused RoPE-Q prologue, complementary pairing,
// dbuf K/V staging, swapped-operand lane-local softmax + defer-max, setprio,
// output in-place into Qp.
// ---------------------------------------------------------------------------
__global__ __launch_bounds__(256, 2) void k_attn(
    const bf16_t* __restrict__ Qp, const bf16_t* __restrict__ Kp,
    const bf16_t* __restrict__ Vt, bf16_t* __restrict__ AO,
    const float* __restrict__ cosT, const float* __restrict__ sinT)
{
  __shared__ bf16_t Ks[2][64 * 128];
  __shared__ bf16_t Vs[2][128 * 64];
  __shared__ bf16_t Ps[4][16 * 72];
  const int tid = threadIdx.x, lane = tid & 63, wave = tid >> 6;
  const int l15 = lane & 15, lg = lane >> 4;
  const int bx = (blockIdx.y < 16) ? (15 - (int)blockIdx.x) : (int)blockIdx.x;
  const int qtile = bx * 4 + wave;
  const int bh = blockIdx.y;
  const int b = bh >> 4, hq = bh & 15, hkv = hq >> 2;

  bf16x8 qf[2][4];
#pragma unroll
  for (int rf = 0; rf < 2; ++rf) {
    int n = qtile * 32 + rf * 16 + l15;
    size_t qrow = (size_t)b * N_ + n;
    const uint8_t* qb = (const uint8_t*)Qp + (qrow * DIM_ + (size_t)hq * HD_) * 2 + lg * 16;
#pragma unroll
    for (int ks = 0; ks < 4; ++ks)
      qf[rf][ks] = *(const bf16x8*)(qb + ks * 64);
    const float* cb = cosT + n * 64 + lg * 8;
    const float* sb = sinT + n * 64 + lg * 8;
    f32x4 c0a = *(const f32x4*)cb,        c0b = *(const f32x4*)(cb + 4);
    f32x4 c1a = *(const f32x4*)(cb + 32), c1b = *(const f32x4*)(cb + 36);
    f32x4 s0a = *(const f32x4*)sb,        s0b = *(const f32x4*)(sb + 4);
    f32x4 s1a = *(const f32x4*)(sb + 32), s1b = *(const f32x4*)(sb + 36);
#pragma unroll
    for (int e = 0; e < 8; ++e) {
      float c0 = e < 4 ? c0a[e] : c0b[e - 4], s0 = e < 4 ? s0a[e] : s0b[e - 4];
      float c1 = e < 4 ? c1a[e] : c1b[e - 4], s1 = e < 4 ? s1a[e] : s1b[e - 4];
      float a0 = (float)qf[rf][0][e], b0 = (float)qf[rf][2][e];
      float a1 = (float)qf[rf][1][e], b1 = (float)qf[rf][3][e];
      qf[rf][0][e] = (bf16_t)((a0 * c0 - b0 * s0) * SCALE_);
      qf[rf][2][e] = (bf16_t)((b0 * c0 + a0 * s0) * SCALE_);
      qf[rf][1][e] = (bf16_t)((a1 * c1 - b1 * s1) * SCALE_);
      qf[rf][3][e] = (bf16_t)((b1 * c1 + a1 * s1) * SCALE_);
    }
  }

  float m[2] = {-1e30f, -1e30f};
  float ln[2] = {0.f, 0.f};
  f32x4 o[2][8] = {};

  const uint8_t* KpB = (const uint8_t*)Kp + ((size_t)b * N_ * KVD_ + (size_t)hkv * HD_) * 2;
  const uint8_t* VtB = (const uint8_t*)Vt + (size_t)(b * HKV_ + hkv) * HD_ * (size_t)N_ * 2;
  uint8_t* PwB = (uint8_t*)Ps[wave];

  const int Tw   = qtile / 2 + 1;
  const int Tmax = 2 * bx + 2;

  auto stage = [&](int buf, int t) {
    uint8_t* KsB = (uint8_t*)Ks[buf];
    uint8_t* VsB = (uint8_t*)Vs[buf];
#pragma unroll
    for (int r = 0; r < 4; ++r) {
      int o16 = r * 4096 + wave * 1024 + lane * 16;
      int row = o16 >> 8;
      int colB = (o16 & 255) ^ ((row & 7) << 4);
      ld_g2l(KsB + r * 4096 + wave * 1024,
             KpB + (size_t)(t * 64 + row) * (KVD_ * 2) + colB);
    }
#pragma unroll
    for (int r = 0; r < 4; ++r) {
      int o16 = r * 4096 + wave * 1024 + lane * 16;
      int dd = o16 >> 7;
      int colB = (o16 & 127) ^ ((dd & 7) << 4);
      ld_g2l(VsB + r * 4096 + wave * 1024,
             VtB + (size_t)dd * (N_ * 2) + t * 128 + colB);
    }
  };

  stage(0, 0);
  __syncthreads();
  int cur = 0;

  for (int t = 0; t < Tmax; ++t) {
    if (t + 1 < Tmax) stage(cur ^ 1, t + 1);

    if (t < Tw) {
      const uint8_t* KsB = (const uint8_t*)Ks[cur];
      const uint8_t* VsB = (const uint8_t*)Vs[cur];

      f32x4 s4[2][4] = {};
      __builtin_amdgcn_s_setprio(1);
#pragma unroll
      for (int ks = 0; ks < 4; ++ks) {
        int koff = ks * 64 + lg * 16;
#pragma unroll
        for (int kb = 0; kb < 4; ++kb) {
          int row = kb * 16 + l15;
          bf16x8 kf = *(const bf16x8*)(KsB + row * 256 + (koff ^ ((row & 7) << 4)));
          s4[0][kb] = __builtin_amdgcn_mfma_f32_16x16x32_bf16(kf, qf[0][ks], s4[0][kb], 0, 0, 0);
          s4[1][kb] = __builtin_amdgcn_mfma_f32_16x16x32_bf16(kf, qf[1][ks], s4[1][kb], 0, 0, 0);
        }
      }
      __builtin_amdgcn_s_setprio(0);

      if (t == Tw - 1) {
#pragma unroll
        for (int rf = 0; rf < 2; ++rf) {
          int q = qtile * 32 + rf * 16 + l15;
#pragma unroll
          for (int kb = 0; kb < 4; ++kb) {
            int key = t * 64 + kb * 16 + lg * 4;
#pragma unroll
            for (int rr = 0; rr < 4; ++rr)
              if (key + rr > q) s4[rf][kb][rr] = -1e30f;
          }
        }
      }

      bf16x8 pf[2][2];
#pragma unroll
      for (int rf = 0; rf < 2; ++rf) {
        f32x4 mx = vmax4(vmax4(s4[rf][0], s4[rf][1]), vmax4(s4[rf][2], s4[rf][3]));
        float rm = fmaxf(fmaxf(mx[0], mx[1]), fmaxf(mx[2], mx[3]));
        rm = fmaxf(rm, __shfl_xor(rm, 16));
        rm = fmaxf(rm, __shfl_xor(rm, 32));

        const bool defer = __all(rm <= m[rf] + 8.0f);
        float mn = defer ? m[rf] : fmaxf(m[rf], rm);
        float sc = defer ? 1.0f : __expf(m[rf] - mn);

        f32x4 p[4];
        f32x4 psum = {0.f, 0.f, 0.f, 0.f};
#pragma unroll
        for (int kb = 0; kb < 4; ++kb) {
#pragma unroll
          for (int rr = 0; rr < 4; ++rr)
            p[kb][rr] = __expf(s4[rf][kb][rr] - mn);
          psum += p[kb];
        }
        float rs = (psum[0] + psum[1]) + (psum[2] + psum[3]);
        rs += __shfl_xor(rs, 16);
        rs += __shfl_xor(rs, 32);
        ln[rf] = ln[rf] * sc + rs;
        m[rf] = mn;

        if (!defer) {
#pragma unroll
          for (int db = 0; db < 8; ++db) o[rf][db] *= sc;
        }

#pragma unroll
        for (int kb = 0; kb < 4; ++kb) {
          union { bf16_t h[4]; uint2 u; } pk;
          pk.h[0] = (bf16_t)p[kb][0]; pk.h[1] = (bf16_t)p[kb][1];
          pk.h[2] = (bf16_t)p[kb][2]; pk.h[3] = (bf16_t)p[kb][3];
          *(uint2*)(PwB + l15 * 144 + kb * 32 + lg * 8) = pk.u;
        }
        pf[rf][0] = *(const bf16x8*)(PwB + l15 * 144 + lg * 16);
        pf[rf][1] = *(const bf16x8*)(PwB + l15 * 144 + 64 + lg * 16);
      }

      __builtin_amdgcn_s_setprio(1);
#pragma unroll
      for (int ks2 = 0; ks2 < 2; ++ks2) {
        int koff = ks2 * 64 + lg * 16;
#pragma unroll
        for (int db = 0; db < 8; ++db) {
          int dd = db * 16 + l15;
          bf16x8 vf = *(const bf16x8*)(VsB + dd * 128 + (koff ^ ((dd & 7) << 4)));
          o[0][db] = __builtin_amdgcn_mfma_f32_16x16x32_bf16(vf, pf[0][ks2], o[0][db], 0, 0, 0);
          o[1][db] = __builtin_amdgcn_mfma_f32_16x16x32_bf16(vf, pf[1][ks2], o[1][db], 0, 0, 0);
        }
      }
      __builtin_amdgcn_s_setprio(0);
    }

    __syncthreads();
    cur ^= 1;
  }

#pragma unroll
  for (int rf = 0; rf < 2; ++rf) {
    float iv = 1.f / ln[rf];
    size_t qrow = (size_t)b * N_ + qtile * 32 + rf * 16 + l15;
    uint8_t* ob = (uint8_t*)(AO + qrow * DIM_ + (size_t)hq * HD_);
#pragma unroll
    for (int db = 0; db < 8; ++db) {
      union { bf16_t h[4]; uint2 u; } pk;
      pk.h[0] = (bf16_t)(o[rf][db][0] * iv);
      pk.h[1] = (bf16_t)(o[rf][db][1] * iv);
      pk.h[2] = (bf16_t)(o[rf][db][2] * iv);
      pk.h[3] = (bf16_t)(o[rf][db][3] * iv);
      *(uint2*)(ob + (db * 16 + lg * 4) * 2) = pk.u;
    }
  }
}

// ---------------------------------------------------------------------------
extern "C" void kernel_launch(void* const* d_in, const int* in_sizes, int n_in,
                              void* d_out, int out_size, void* d_ws, size_t ws_size,
                              hipStream_t stream)
{
  if (ws_size < (46u << 20)) return;  // proven sufficient in rounds 3-23

  const float* query = (const float*)d_in[0];
  const float* key   = (const float*)d_in[1];
  const float* value = (const float*)d_in[2];
  const float* Wq = (const float*)d_in[3];
  const float* bq = (const float*)d_in[4];
  const float* Wk = (const float*)d_in[5];
  const float* bk = (const float*)d_in[6];
  const float* Wv = (const float*)d_in[7];
  const float* bv = (const float*)d_in[8];
  const float* Wo = (const float*)d_in[9];
  const float* bo = (const float*)d_in[10];
  float* out = (float*)d_out;

  uint8_t* ws = (uint8_t*)d_ws;
  float*  cosT = (float*)(ws);                       // 0.5 MB
  float*  sinT = (float*)(ws + (512u << 10));        // 0.5 MB
  bf16_t* Qp   = (bf16_t*)(ws + (1u  << 20));        // 16 MB [4096][2048] (+ attn out)
  bf16_t* Kp   = (bf16_t*)(ws + (17u << 20));        // 4 MB  [4096][512]
  bf16_t* Vp   = (bf16_t*)(ws + (21u << 20));        // 4 MB  [4096][512]
  bf16_t* Vt   = (bf16_t*)(ws + (25u << 20));        // 4 MB  [8][128][2048]
  bf16_t* Wqb  = (bf16_t*)(ws + (29u << 20));        // 8 MB  [2048][2048]
  bf16_t* Wkb  = (bf16_t*)(ws + (37u << 20));        // 2 MB  [512][2048]
  bf16_t* Wvb  = (bf16_t*)(ws + (39u << 20));        // 2 MB  [512][2048]
  bf16_t* WobL = (bf16_t*)(ws + (17u << 20));        // late path: over Kp+Vp
  bf16_t* WobE = (bf16_t*)(ws + (41u << 20));        // early path: 8 MB at 41MB

  const bool bigws = ws_size >= (50ull << 20);       // early-Wo needs 49 MB

  k_sincos<<<512, 256, 0, stream>>>(cosT, sinT);

  if (bigws) {
    k_cvt4<<<10240, 256, 0, stream>>>(Wq, Wqb, 4194304,
                                      Wk, Wkb, 1048576,
                                      Wv, Wvb, 1048576,
                                      Wo, WobE, 4194304);
  } else {
    k_cvt4<<<6144, 256, 0, stream>>>(Wq, Wqb, 4194304,
                                     Wk, Wkb, 1048576,
                                     Wv, Wvb, 1048576,
                                     nullptr, nullptr, 0);
  }

  // Q+K+V projections: dual-bn + A-reg prefetch
  k_gemm_qkv<<<dim3(32, 8, 3), 256, 0, stream>>>(
      query, Wqb, bq, Qp, key, Wkb, bk, Kp, value, Wvb, bv, Vp);

  // merged RoPE-K + V-transpose (one launch)
  k_ropek_transv<<<1024, 256, 0, stream>>>(Kp, cosT, sinT, Vp, Vt);

  // flash attention: fused RoPE-Q + complementary pairing + dbuf staging
  k_attn<<<dim3(16, 32), 256, 0, stream>>>(Qp, Kp, Vt, Qp, cosT, sinT);

  if (!bigws) {
    k_cvt4<<<4096, 256, 0, stream>>>(Wo, WobL, 4194304,
                                     nullptr, nullptr, 0,
                                     nullptr, nullptr, 0,
                                     nullptr, nullptr, 0);
  }

  // Output projection: single-buffer full g2l (best-measured form)
  k_gemm_o<<<dim3(32, 16), 256, 0, stream>>>(
      Qp, bigws ? WobE : WobL, bo, out);
}

// Round 25
// 199.314 us; speedup vs baseline: 1.0473x; 1.0282x over previous
//
#include <hip/hip_runtime.h>
#include <cstdint>

// ---------------------------------------------------------------------------
// GroupedQueryAttention: B=2 N=2048 DIM=2048 HQ=16 HKV=4 HD=128, causal, RoPE.
// f32 I/O, bf16 internals. Round 25 = r24 best (204.9us) + sincos merged into
// the weight-conversion kernel (k_prep), 6 dispatches total:
//  - k_prep: blocks[0,512) sincos table; rest f32->bf16 weight conversion
//  - QKV: dual-bn + A-reg prefetch (48KB LDS, lb(256,2))
//  - merged ropeK+transV; attn (fused RoPE-Q, pairing, dbuf, defer-max)
//  - O-proj: single-buffer full-g2l (lb(256,4)); in-place attn output
// ---------------------------------------------------------------------------

typedef __bf16 bf16_t;
typedef __attribute__((ext_vector_type(8))) __bf16 bf16x8;
typedef __attribute__((ext_vector_type(4))) float f32x4;

#define B_    2
#define N_    2048
#define DIM_  2048
#define HQ_   16
#define HKV_  4
#define HD_   128
#define KVD_  512
#define SCALE_ 0.08838834764831845f  // 128^-0.5

// async global->LDS, 16B per lane. lds dest must be wave-uniform base.
static __device__ __forceinline__ void ld_g2l(void* lds, const void* g) {
  __builtin_amdgcn_global_load_lds((__attribute__((address_space(1))) void*)g,
                                   (__attribute__((address_space(3))) void*)lds,
                                   16, 0, 0);
}

static __device__ __forceinline__ f32x4 vmax4(f32x4 a, f32x4 b) {
  f32x4 r;
  r[0] = fmaxf(a[0], b[0]); r[1] = fmaxf(a[1], b[1]);
  r[2] = fmaxf(a[2], b[2]); r[3] = fmaxf(a[3], b[3]);
  return r;
}

// ---------------------------------------------------------------------------
// k_prep: blocks [0,512) build cos/sin tables [2048][64] f32
//         (inv_freq = 10000^(-i/64), base_adj==1); remaining blocks convert
//         up to four f32 tensors to bf16 (4 elems/thread).
// ---------------------------------------------------------------------------
__global__ void k_prep(float* __restrict__ cosT, float* __restrict__ sinT,
                       const float* __restrict__ s0, bf16_t* __restrict__ d0, int n0,
                       const float* __restrict__ s1, bf16_t* __restrict__ d1, int n1,
                       const float* __restrict__ s2, bf16_t* __restrict__ d2, int n2,
                       const float* __restrict__ s3, bf16_t* __restrict__ d3, int n3)
{
  if (blockIdx.x < 512) {
    int idx = blockIdx.x * 256 + threadIdx.x;  // 2048*64
    int i = idx & 63;
    int n = idx >> 6;
    float inv = expf(-(float)i * (9.210340371976184f / 64.0f));  // ln(1e4)/64
    float ang = (float)n * inv;
    cosT[idx] = cosf(ang);
    sinT[idx] = sinf(ang);
    return;
  }
  int i = ((blockIdx.x - 512) * 256 + threadIdx.x) * 4;
  const float* s; bf16_t* d; int off;
  if (i < n0)                     { s = s0; d = d0; off = i; }
  else if (i < n0 + n1)           { s = s1; d = d1; off = i - n0; }
  else if (i < n0 + n1 + n2)      { s = s2; d = d2; off = i - n0 - n1; }
  else if (i < n0 + n1 + n2 + n3) { s = s3; d = d3; off = i - n0 - n1 - n2; }
  else return;
  f32x4 v = *(const f32x4*)(s + off);
  union { bf16_t h[4]; uint2 u; } pk;
  pk.h[0] = (bf16_t)v[0]; pk.h[1] = (bf16_t)v[1];
  pk.h[2] = (bf16_t)v[2]; pk.h[3] = (bf16_t)v[3];
  *(uint2*)(d + off) = pk.u;
}

// ---------------------------------------------------------------------------
// QKV projections: dual-bn + A-reg prefetch. One staged A f32 tile [128][64]
// feeds TWO 128-col W bf16 tiles; A loads for round t+1 issued after the
// barrier, hidden under the 64-MFMA compute. BK=64, XOR swizzle
// byte^((row&7)<<4). z=0 Q (by<8), z=1 K, z=2 V (by<2). LDS 48KB.
// ---------------------------------------------------------------------------
__global__ __launch_bounds__(256, 2) void k_gemm_qkv(
    const float* __restrict__ q, const bf16_t* __restrict__ Wqb,
    const float* __restrict__ bq, bf16_t* __restrict__ Qp,
    const float* __restrict__ k, const bf16_t* __restrict__ Wkb,
    const float* __restrict__ bk, bf16_t* __restrict__ Kp,
    const float* __restrict__ v, const bf16_t* __restrict__ Wvb,
    const float* __restrict__ bv, bf16_t* __restrict__ Vp)
{
  __shared__ bf16_t As[128 * 64];
  __shared__ bf16_t Bs[2][128 * 64];
  const int z = blockIdx.z;
  if (z != 0 && blockIdx.y >= 2) return;
  const float* A; const bf16_t* W; const float* bias; bf16_t* C; int Nn;
  if (z == 0)      { A = q; W = Wqb; bias = bq; C = Qp; Nn = 2048; }
  else if (z == 1) { A = k; W = Wkb; bias = bk; C = Kp; Nn = 512; }
  else             { A = v; W = Wvb; bias = bv; C = Vp; Nn = 512; }

  const int tid  = threadIdx.x;
  const int lane = tid & 63;
  const int wave = tid >> 6;
  const int l15  = lane & 15;
  const int lg   = lane >> 4;
  const int bm = blockIdx.x;
  const int bn0 = blockIdx.y * 2, bn1 = bn0 + 1;
  const int wr = (wave >> 1) * 64, wc = (wave & 1) * 64;
  const int K = 2048;

  f32x4 acc0[4][4] = {};
  f32x4 acc1[4][4] = {};

  uint8_t* AsB = (uint8_t*)As;
  uint8_t* Bs0 = (uint8_t*)Bs[0];
  uint8_t* Bs1 = (uint8_t*)Bs[1];
  const uint8_t* Wb0 = (const uint8_t*)W + (size_t)(bn0 * 128) * K * 2;
  const uint8_t* Wb1 = (const uint8_t*)W + (size_t)(bn1 * 128) * K * 2;

  f32x4 arLo[4], arHi[4];   // A f32 prefetch: 32 elems/thread

  auto loadA = [&](int k0) {
#pragma unroll
    for (int i = 0; i < 4; ++i) {
      int c = i * 256 + tid;
      int row = c >> 3;
      int k8  = (c & 7) * 8;
      const float* ap = A + (size_t)(bm * 128 + row) * K + k0 + k8;
      arLo[i] = *(const f32x4*)ap;
      arHi[i] = *(const f32x4*)(ap + 4);
    }
  };
  auto writeA = [&]() {
#pragma unroll
    for (int i = 0; i < 4; ++i) {
      int c = i * 256 + tid;
      int row = c >> 3;
      int k8  = (c & 7) * 8;
      bf16x8 va;
      f32x4 lo = arLo[i], hi = arHi[i];
      va[0] = (bf16_t)lo[0]; va[1] = (bf16_t)lo[1];
      va[2] = (bf16_t)lo[2]; va[3] = (bf16_t)lo[3];
      va[4] = (bf16_t)hi[0]; va[5] = (bf16_t)hi[1];
      va[6] = (bf16_t)hi[2]; va[7] = (bf16_t)hi[3];
      int sw = (k8 * 2) ^ ((row & 7) << 4);
      *(bf16x8*)(AsB + row * 128 + sw) = va;
    }
  };

  loadA(0);   // prologue

  for (int k0 = 0; k0 < K; k0 += 64) {
#pragma unroll
    for (int r = 0; r < 4; ++r) {
      int o = r * 4096 + wave * 1024 + lane * 16;
      int row = o >> 7;
      int colB = (o & 127) ^ ((row & 7) << 4);
      size_t goff = (size_t)row * (K * 2) + (size_t)k0 * 2 + colB;
      ld_g2l(Bs0 + r * 4096 + wave * 1024, Wb0 + goff);
      ld_g2l(Bs1 + r * 4096 + wave * 1024, Wb1 + goff);
    }
    writeA();                 // cvt + ds_write only (loads already arrived)
    const bool more = (k0 + 64 < K);
    __syncthreads();          // W staged, A visible
    if (more) loadA(k0 + 64); // issue next A loads; hidden by MFMAs
    __builtin_amdgcn_s_setprio(1);
#pragma unroll
    for (int kk = 0; kk < 2; ++kk) {
      const int koff = kk * 64 + (lg << 4);
      bf16x8 fa[4], fb[4];
#pragma unroll
      for (int fi = 0; fi < 4; ++fi) {
        int row = wr + fi * 16 + l15;
        fa[fi] = *(const bf16x8*)(AsB + row * 128 + (koff ^ ((row & 7) << 4)));
      }
#pragma unroll
      for (int fj = 0; fj < 4; ++fj) {
        int row = wc + fj * 16 + l15;
        fb[fj] = *(const bf16x8*)(Bs0 + row * 128 + (koff ^ ((row & 7) << 4)));
      }
#pragma unroll
      for (int fi = 0; fi < 4; ++fi)
#pragma unroll
        for (int fj = 0; fj < 4; ++fj)
          acc0[fi][fj] = __builtin_amdgcn_mfma_f32_16x16x32_bf16(
              fa[fi], fb[fj], acc0[fi][fj], 0, 0, 0);
#pragma unroll
      for (int fj = 0; fj < 4; ++fj) {
        int row = wc + fj * 16 + l15;
        fb[fj] = *(const bf16x8*)(Bs1 + row * 128 + (koff ^ ((row & 7) << 4)));
      }
#pragma unroll
      for (int fi = 0; fi < 4; ++fi)
#pragma unroll
        for (int fj = 0; fj < 4; ++fj)
          acc1[fi][fj] = __builtin_amdgcn_mfma_f32_16x16x32_bf16(
              fa[fi], fb[fj], acc1[fi][fj], 0, 0, 0);
    }
    __builtin_amdgcn_s_setprio(0);
    __syncthreads();
  }

  const int r0 = lg * 4;
#pragma unroll
  for (int fi = 0; fi < 4; ++fi) {
#pragma unroll
    for (int rr = 0; rr < 4; ++rr) {
      int grow = bm * 128 + wr + fi * 16 + r0 + rr;
      size_t rowoff = (size_t)grow * Nn;
#pragma unroll
      for (int fj = 0; fj < 4; ++fj) {
        int gc0 = bn0 * 128 + wc + fj * 16 + l15;
        int gc1 = bn1 * 128 + wc + fj * 16 + l15;
        C[rowoff + gc0] = (bf16_t)(acc0[fi][fj][rr] + bias[gc0]);
        C[rowoff + gc1] = (bf16_t)(acc1[fi][fj][rr] + bias[gc1]);
      }
    }
  }
}

// ---------------------------------------------------------------------------
// O projection: A bf16 g2l, W bf16 g2l, C f32. 128x128, BK=64, single-buffer
// (best-measured form: lb(256,4), 32KB LDS).
// ---------------------------------------------------------------------------
__global__ __launch_bounds__(256, 4) void k_gemm_o(
    const bf16_t* __restrict__ Ain, const bf16_t* __restrict__ Wob,
    const float* __restrict__ bo, float* __restrict__ out)
{
  __shared__ bf16_t As[128 * 64];
  __shared__ bf16_t Bs[128 * 64];
  const int tid  = threadIdx.x;
  const int lane = tid & 63;
  const int wave = tid >> 6;
  const int l15  = lane & 15;
  const int lg   = lane >> 4;
  const int bm = blockIdx.x, bn = blockIdx.y;
  const int wr = (wave >> 1) * 64, wc = (wave & 1) * 64;
  const int K = 2048, N = 2048;

  f32x4 acc[4][4] = {};
  uint8_t* AsB = (uint8_t*)As;
  uint8_t* BsB = (uint8_t*)Bs;
  const uint8_t* Wbase = (const uint8_t*)Wob + (size_t)(bn * 128) * K * 2;
  const uint8_t* Abase = (const uint8_t*)Ain + (size_t)(bm * 128) * K * 2;

  for (int k0 = 0; k0 < K; k0 += 64) {
    for (int r = 0; r < 4; ++r) {
      int o = r * 4096 + wave * 1024 + lane * 16;
      int row = o >> 7;
      int colB = (o & 127) ^ ((row & 7) << 4);
      size_t goff = (size_t)row * (K * 2) + (size_t)k0 * 2 + colB;
      ld_g2l(BsB + r * 4096 + wave * 1024, Wbase + goff);
      ld_g2l(AsB + r * 4096 + wave * 1024, Abase + goff);
    }
    __syncthreads();
    for (int kk = 0; kk < 2; ++kk) {
      const int koff = kk * 64 + (lg << 4);
      bf16x8 fa[4], fb[4];
      for (int fi = 0; fi < 4; ++fi) {
        int row = wr + fi * 16 + l15;
        fa[fi] = *(const bf16x8*)(AsB + row * 128 + (koff ^ ((row & 7) << 4)));
      }
      for (int fj = 0; fj < 4; ++fj) {
        int row = wc + fj * 16 + l15;
        fb[fj] = *(const bf16x8*)(BsB + row * 128 + (koff ^ ((row & 7) << 4)));
      }
      for (int fi = 0; fi < 4; ++fi)
        for (int fj = 0; fj < 4; ++fj)
          acc[fi][fj] = __builtin_amdgcn_mfma_f32_16x16x32_bf16(
              fa[fi], fb[fj], acc[fi][fj], 0, 0, 0);
    }
    __syncthreads();
  }

  const int r0 = lg * 4;
  for (int fi = 0; fi < 4; ++fi) {
    for (int rr = 0; rr < 4; ++rr) {
      int grow = bm * 128 + wr + fi * 16 + r0 + rr;
      size_t rowoff = (size_t)grow * N;
      for (int fj = 0; fj < 4; ++fj) {
        int gcol = bn * 128 + wc + fj * 16 + l15;
        out[rowoff + gcol] = acc[fi][fj][rr] + bo[gcol];
      }
    }
  }
}

// ---------------------------------------------------------------------------
// Merged: blocks [0,512) = RoPE on Kp (lgnh=2); blocks [512,1024) = V transpose.
// ---------------------------------------------------------------------------
__global__ void k_ropek_transv(bf16_t* __restrict__ Kp,
                               const float* __restrict__ cosT,
                               const float* __restrict__ sinT,
                               const bf16_t* __restrict__ Vp,
                               bf16_t* __restrict__ Vt)
{
  __shared__ bf16_t tile[64][72];
  const int tid = threadIdx.x;
  if (blockIdx.x < 512) {
    int idx = blockIdx.x * 256 + tid;
    int j = idx & 7;
    int h = (idx >> 3) & 3;
    int row = idx >> 5;
    int n = row & (N_ - 1);
    int d0 = j * 8;
    const float* cp = cosT + (n << 6) + d0;
    const float* sp = sinT + (n << 6) + d0;
    f32x4 c0 = *(const f32x4*)cp,  c1 = *(const f32x4*)(cp + 4);
    f32x4 s0 = *(const f32x4*)sp,  s1 = *(const f32x4*)(sp + 4);
    bf16_t* xb = Kp + (size_t)row * 512 + (h << 7) + d0;
    bf16x8 x1 = *(const bf16x8*)xb;
    bf16x8 x2 = *(const bf16x8*)(xb + 64);
    bf16x8 o1, o2;
#pragma unroll
    for (int e = 0; e < 8; ++e) {
      float c = e < 4 ? c0[e] : c1[e - 4];
      float s = e < 4 ? s0[e] : s1[e - 4];
      float a = (float)x1[e], bvl = (float)x2[e];
      o1[e] = (bf16_t)(a * c - bvl * s);
      o2[e] = (bf16_t)(bvl * c + a * s);
    }
    *(bf16x8*)xb = o1;
    *(bf16x8*)(xb + 64) = o2;
    return;
  }
  const int bid = blockIdx.x - 512;
  const int r0 = (bid & 63) * 64;
  const int d0 = (bid >> 6) * 64;
  for (int r = 0; r < 2; ++r) {
    int n = r * 32 + (tid >> 3);
    int dc = (tid & 7) * 8;
    *(uint4*)&tile[n][dc] = *(const uint4*)(Vp + (size_t)(r0 + n) * KVD_ + d0 + dc);
  }
  __syncthreads();
  const int b = r0 >> 11;
  const int nseq = r0 & (N_ - 1);
  for (int r = 0; r < 2; ++r) {
    int dd = r * 32 + (tid >> 3);
    int nc = (tid & 7) * 8;
    int dglob = d0 + dd;
    int hkv = dglob >> 7, dloc = dglob & 127;
    union { bf16_t h[8]; uint4 v; } pk;
    for (int j = 0; j < 8; ++j) pk.h[j] = tile[nc + j][dd];
    size_t drow = (size_t)(b * HKV_ + hkv) * 128 + dloc;
    *(uint4*)(Vt + drow * N_ + nseq + nc) = pk.v;
  }
}

// ---------------------------------------------------------------------------
// Flash attention, causal GQA: fused RoPE-Q prologue, complementary pairing,
// dbuf K/V staging, swapped-operand lane-local softmax + defer-max, setprio,
// output in-place into Qp.
// ---------------------------------------------------------------------------
__global__ __launch_bounds__(256, 2) void k_attn(
    const bf16_t* __restrict__ Qp, const bf16_t* __restrict__ Kp,
    const bf16_t* __restrict__ Vt, bf16_t* __restrict__ AO,
    const float* __restrict__ cosT, const float* __restrict__ sinT)
{
  __shared__ bf16_t Ks[2][64 * 128];
  __shared__ bf16_t Vs[2][128 * 64];
  __shared__ bf16_t Ps[4][16 * 72];
  const int tid = threadIdx.x, lane = tid & 63, wave = tid >> 6;
  const int l15 = lane & 15, lg = lane >> 4;
  const int bx = (blockIdx.y < 16) ? (15 - (int)blockIdx.x) : (int)blockIdx.x;
  const int qtile = bx * 4 + wave;
  const int bh = blockIdx.y;
  const int b = bh >> 4, hq = bh & 15, hkv = hq >> 2;

  bf16x8 qf[2][4];
#pragma unroll
  for (int rf = 0; rf < 2; ++rf) {
    int n = qtile * 32 + rf * 16 + l15;
    size_t qrow = (size_t)b * N_ + n;
    const uint8_t* qb = (const uint8_t*)Qp + (qrow * DIM_ + (size_t)hq * HD_) * 2 + lg * 16;
#pragma unroll
    for (int ks = 0; ks < 4; ++ks)
      qf[rf][ks] = *(const bf16x8*)(qb + ks * 64);
    const float* cb = cosT + n * 64 + lg * 8;
    const float* sb = sinT + n * 64 + lg * 8;
    f32x4 c0a = *(const f32x4*)cb,        c0b = *(const f32x4*)(cb + 4);
    f32x4 c1a = *(const f32x4*)(cb + 32), c1b = *(const f32x4*)(cb + 36);
    f32x4 s0a = *(const f32x4*)sb,        s0b = *(const f32x4*)(sb + 4);
    f32x4 s1a = *(const f32x4*)(sb + 32), s1b = *(const f32x4*)(sb + 36);
#pragma unroll
    for (int e = 0; e < 8; ++e) {
      float c0 = e < 4 ? c0a[e] : c0b[e - 4], s0 = e < 4 ? s0a[e] : s0b[e - 4];
      float c1 = e < 4 ? c1a[e] : c1b[e - 4], s1 = e < 4 ? s1a[e] : s1b[e - 4];
      float a0 = (float)qf[rf][0][e], b0 = (float)qf[rf][2][e];
      float a1 = (float)qf[rf][1][e], b1 = (float)qf[rf][3][e];
      qf[rf][0][e] = (bf16_t)((a0 * c0 - b0 * s0) * SCALE_);
      qf[rf][2][e] = (bf16_t)((b0 * c0 + a0 * s0) * SCALE_);
      qf[rf][1][e] = (bf16_t)((a1 * c1 - b1 * s1) * SCALE_);
      qf[rf][3][e] = (bf16_t)((b1 * c1 + a1 * s1) * SCALE_);
    }
  }

  float m[2] = {-1e30f, -1e30f};
  float ln[2] = {0.f, 0.f};
  f32x4 o[2][8] = {};

  const uint8_t* KpB = (const uint8_t*)Kp + ((size_t)b * N_ * KVD_ + (size_t)hkv * HD_) * 2;
  const uint8_t* VtB = (const uint8_t*)Vt + (size_t)(b * HKV_ + hkv) * HD_ * (size_t)N_ * 2;
  uint8_t* PwB = (uint8_t*)Ps[wave];

  const int Tw   = qtile / 2 + 1;
  const int Tmax = 2 * bx + 2;

  auto stage = [&](int buf, int t) {
    uint8_t* KsB = (uint8_t*)Ks[buf];
    uint8_t* VsB = (uint8_t*)Vs[buf];
#pragma unroll
    for (int r = 0; r < 4; ++r) {
      int o16 = r * 4096 + wave * 1024 + lane * 16;
      int row = o16 >> 8;
      int colB = (o16 & 255) ^ ((row & 7) << 4);
      ld_g2l(KsB + r * 4096 + wave * 1024,
             KpB + (size_t)(t * 64 + row) * (KVD_ * 2) + colB);
    }
#pragma unroll
    for (int r = 0; r < 4; ++r) {
      int o16 = r * 4096 + wave * 1024 + lane * 16;
      int dd = o16 >> 7;
      int colB = (o16 & 127) ^ ((dd & 7) << 4);
      ld_g2l(VsB + r * 4096 + wave * 1024,
             VtB + (size_t)dd * (N_ * 2) + t * 128 + colB);
    }
  };

  stage(0, 0);
  __syncthreads();
  int cur = 0;

  for (int t = 0; t < Tmax; ++t) {
    if (t + 1 < Tmax) stage(cur ^ 1, t + 1);

    if (t < Tw) {
      const uint8_t* KsB = (const uint8_t*)Ks[cur];
      const uint8_t* VsB = (const uint8_t*)Vs[cur];

      f32x4 s4[2][4] = {};
      __builtin_amdgcn_s_setprio(1);
#pragma unroll
      for (int ks = 0; ks < 4; ++ks) {
        int koff = ks * 64 + lg * 16;
#pragma unroll
        for (int kb = 0; kb < 4; ++kb) {
          int row = kb * 16 + l15;
          bf16x8 kf = *(const bf16x8*)(KsB + row * 256 + (koff ^ ((row & 7) << 4)));
          s4[0][kb] = __builtin_amdgcn_mfma_f32_16x16x32_bf16(kf, qf[0][ks], s4[0][kb], 0, 0, 0);
          s4[1][kb] = __builtin_amdgcn_mfma_f32_16x16x32_bf16(kf, qf[1][ks], s4[1][kb], 0, 0, 0);
        }
      }
      __builtin_amdgcn_s_setprio(0);

      if (t == Tw - 1) {
#pragma unroll
        for (int rf = 0; rf < 2; ++rf) {
          int q = qtile * 32 + rf * 16 + l15;
#pragma unroll
          for (int kb = 0; kb < 4; ++kb) {
            int key = t * 64 + kb * 16 + lg * 4;
#pragma unroll
            for (int rr = 0; rr < 4; ++rr)
              if (key + rr > q) s4[rf][kb][rr] = -1e30f;
          }
        }
      }

      bf16x8 pf[2][2];
#pragma unroll
      for (int rf = 0; rf < 2; ++rf) {
        f32x4 mx = vmax4(vmax4(s4[rf][0], s4[rf][1]), vmax4(s4[rf][2], s4[rf][3]));
        float rm = fmaxf(fmaxf(mx[0], mx[1]), fmaxf(mx[2], mx[3]));
        rm = fmaxf(rm, __shfl_xor(rm, 16));
        rm = fmaxf(rm, __shfl_xor(rm, 32));

        const bool defer = __all(rm <= m[rf] + 8.0f);
        float mn = defer ? m[rf] : fmaxf(m[rf], rm);
        float sc = defer ? 1.0f : __expf(m[rf] - mn);

        f32x4 p[4];
        f32x4 psum = {0.f, 0.f, 0.f, 0.f};
#pragma unroll
        for (int kb = 0; kb < 4; ++kb) {
#pragma unroll
          for (int rr = 0; rr < 4; ++rr)
            p[kb][rr] = __expf(s4[rf][kb][rr] - mn);
          psum += p[kb];
        }
        float rs = (psum[0] + psum[1]) + (psum[2] + psum[3]);
        rs += __shfl_xor(rs, 16);
        rs += __shfl_xor(rs, 32);
        ln[rf] = ln[rf] * sc + rs;
        m[rf] = mn;

        if (!defer) {
#pragma unroll
          for (int db = 0; db < 8; ++db) o[rf][db] *= sc;
        }

#pragma unroll
        for (int kb = 0; kb < 4; ++kb) {
          union { bf16_t h[4]; uint2 u; } pk;
          pk.h[0] = (bf16_t)p[kb][0]; pk.h[1] = (bf16_t)p[kb][1];
          pk.h[2] = (bf16_t)p[kb][2]; pk.h[3] = (bf16_t)p[kb][3];
          *(uint2*)(PwB + l15 * 144 + kb * 32 + lg * 8) = pk.u;
        }
        pf[rf][0] = *(const bf16x8*)(PwB + l15 * 144 + lg * 16);
        pf[rf][1] = *(const bf16x8*)(PwB + l15 * 144 + 64 + lg * 16);
      }

      __builtin_amdgcn_s_setprio(1);
#pragma unroll
      for (int ks2 = 0; ks2 < 2; ++ks2) {
        int koff = ks2 * 64 + lg * 16;
#pragma unroll
        for (int db = 0; db < 8; ++db) {
          int dd = db * 16 + l15;
          bf16x8 vf = *(const bf16x8*)(VsB + dd * 128 + (koff ^ ((dd & 7) << 4)));
          o[0][db] = __builtin_amdgcn_mfma_f32_16x16x32_bf16(vf, pf[0][ks2], o[0][db], 0, 0, 0);
          o[1][db] = __builtin_amdgcn_mfma_f32_16x16x32_bf16(vf, pf[1][ks2], o[1][db], 0, 0, 0);
        }
      }
      __builtin_amdgcn_s_setprio(0);
    }

    __syncthreads();
    cur ^= 1;
  }

#pragma unroll
  for (int rf = 0; rf < 2; ++rf) {
    float iv = 1.f / ln[rf];
    size_t qrow = (size_t)b * N_ + qtile * 32 + rf * 16 + l15;
    uint8_t* ob = (uint8_t*)(AO + qrow * DIM_ + (size_t)hq * HD_);
#pragma unroll
    for (int db = 0; db < 8; ++db) {
      union { bf16_t h[4]; uint2 u; } pk;
      pk.h[0] = (bf16_t)(o[rf][db][0] * iv);
      pk.h[1] = (bf16_t)(o[rf][db][1] * iv);
      pk.h[2] = (bf16_t)(o[rf][db][2] * iv);
      pk.h[3] = (bf16_t)(o[rf][db][3] * iv);
      *(uint2*)(ob + (db * 16 + lg * 4) * 2) = pk.u;
    }
  }
}

// ---------------------------------------------------------------------------
extern "C" void kernel_launch(void* const* d_in, const int* in_sizes, int n_in,
                              void* d_out, int out_size, void* d_ws, size_t ws_size,
                              hipStream_t stream)
{
  if (ws_size < (46u << 20)) return;  // proven sufficient in rounds 3-24

  const float* query = (const float*)d_in[0];
  const float* key   = (const float*)d_in[1];
  const float* value = (const float*)d_in[2];
  const float* Wq = (const float*)d_in[3];
  const float* bq = (const float*)d_in[4];
  const float* Wk = (const float*)d_in[5];
  const float* bk = (const float*)d_in[6];
  const float* Wv = (const float*)d_in[7];
  const float* bv = (const float*)d_in[8];
  const float* Wo = (const float*)d_in[9];
  const float* bo = (const float*)d_in[10];
  float* out = (float*)d_out;

  uint8_t* ws = (uint8_t*)d_ws;
  float*  cosT = (float*)(ws);                       // 0.5 MB
  float*  sinT = (float*)(ws + (512u << 10));        // 0.5 MB
  bf16_t* Qp   = (bf16_t*)(ws + (1u  << 20));        // 16 MB [4096][2048] (+ attn out)
  bf16_t* Kp   = (bf16_t*)(ws + (17u << 20));        // 4 MB  [4096][512]
  bf16_t* Vp   = (bf16_t*)(ws + (21u << 20));        // 4 MB  [4096][512]
  bf16_t* Vt   = (bf16_t*)(ws + (25u << 20));        // 4 MB  [8][128][2048]
  bf16_t* Wqb  = (bf16_t*)(ws + (29u << 20));        // 8 MB  [2048][2048]
  bf16_t* Wkb  = (bf16_t*)(ws + (37u << 20));        // 2 MB  [512][2048]
  bf16_t* Wvb  = (bf16_t*)(ws + (39u << 20));        // 2 MB  [512][2048]
  bf16_t* WobL = (bf16_t*)(ws + (17u << 20));        // late path: over Kp+Vp
  bf16_t* WobE = (bf16_t*)(ws + (41u << 20));        // early path: 8 MB at 41MB

  const bool bigws = ws_size >= (50ull << 20);       // early-Wo needs 49 MB

  if (bigws) {
    // sincos (512 blocks) + all four weight conversions in ONE launch
    k_prep<<<512 + 10240, 256, 0, stream>>>(cosT, sinT,
                                            Wq, Wqb, 4194304,
                                            Wk, Wkb, 1048576,
                                            Wv, Wvb, 1048576,
                                            Wo, WobE, 4194304);
  } else {
    k_prep<<<512 + 6144, 256, 0, stream>>>(cosT, sinT,
                                           Wq, Wqb, 4194304,
                                           Wk, Wkb, 1048576,
                                           Wv, Wvb, 1048576,
                                           nullptr, nullptr, 0);
  }

  // Q+K+V projections: dual-bn + A-reg prefetch
  k_gemm_qkv<<<dim3(32, 8, 3), 256, 0, stream>>>(
      query, Wqb, bq, Qp, key, Wkb, bk, Kp, value, Wvb, bv, Vp);

  // merged RoPE-K + V-transpose (one launch)
  k_ropek_transv<<<1024, 256, 0, stream>>>(Kp, cosT, sinT, Vp, Vt);

  // flash attention: fused RoPE-Q + complementary pairing + dbuf staging
  k_attn<<<dim3(16, 32), 256, 0, stream>>>(Qp, Kp, Vt, Qp, cosT, sinT);

  if (!bigws) {
    k_prep<<<4096, 256, 0, stream>>>(nullptr, nullptr,   // no sincos blocks
                                     Wo, WobL, 4194304,
                                     nullptr, nullptr, 0,
                                     nullptr, nullptr, 0,
                                     nullptr, nullptr, 0);
  }

  // Output projection: single-buffer full g2l (best-measured form)
  k_gemm_o<<<dim3(32, 16), 256, 0, stream>>>(
      Qp, bigws ? WobE : WobL, bo, out);
}